// Round 9
// baseline (9122.533 us; speedup 1.0000x reference)
//
#include <hip/hip_runtime.h>
#include <hip/hip_bf16.h>
#include <hip/hip_fp16.h>
#include <math.h>

#define NW 1024
#define TC 16
#define EC 128
#define EW 300
#define HID 512
#define H2 256
#define GATES 1024
#define KC (EC + H2)   // 384
#define KW (EW + HID)  // 812
#define NPOS 48
#define NNER 16

typedef _Float16 h2v __attribute__((ext_vector_type(2)));
union U32H { unsigned int u; h2v h; float f; };

__device__ __forceinline__ float sigf(float x) { return 1.f / (1.f + expf(-x)); }

// ---------------- char LSTM gate GEMM: z[d][n][g] = x_t[n]·Wih[g] + h[n]·Whh[g] ----------------
__global__ __launch_bounds__(256)
void char_gate_gemm(int s,
    const float* __restrict__ char_emb, const int* __restrict__ char_seq,
    const float* __restrict__ Wih_f, const float* __restrict__ Whh_f,
    const float* __restrict__ Wih_b, const float* __restrict__ Whh_b,
    const float* __restrict__ hbuf,   // [par][dir][NW][H2]
    float* __restrict__ zbuf)         // [dir][NW][GATES]
{
    const int d = blockIdx.z;
    const float* Wih = d ? Wih_b : Wih_f;
    const float* Whh = d ? Whh_b : Whh_f;
    const int t_time = d ? (TC - 1 - s) : s;
    const float* hprev = hbuf + (size_t)((s & 1) * 2 + d) * NW * H2;

    __shared__ float As[16][65];
    __shared__ float Bs[16][65];
    const int tid = threadIdx.x;
    const int tx = tid & 15, ty = tid >> 4;
    const int row0 = blockIdx.x * 64;
    const int col0 = blockIdx.y * 64;
    float acc[4][4] = {};
    for (int kb = 0; kb < KC; kb += 16) {
        #pragma unroll
        for (int q = 0; q < 4; ++q) {
            int idx = tid + q * 256;
            int mm = idx >> 4, kk = idx & 15;
            int k = kb + kk;
            int n = row0 + mm;
            float av;
            if (k < EC) {
                int ci = char_seq[n * TC + t_time];
                av = char_emb[(size_t)ci * EC + k];
            } else {
                av = (s == 0) ? 0.f : hprev[(size_t)n * H2 + (k - EC)];
            }
            As[kk][mm] = av;
            int g = col0 + mm;
            Bs[kk][mm] = (k < EC) ? Wih[(size_t)g * EC + k] : Whh[(size_t)g * H2 + (k - EC)];
        }
        __syncthreads();
        #pragma unroll
        for (int kk = 0; kk < 16; ++kk) {
            float a[4], b[4];
            #pragma unroll
            for (int i = 0; i < 4; ++i) a[i] = As[kk][ty * 4 + i];
            #pragma unroll
            for (int j = 0; j < 4; ++j) b[j] = Bs[kk][tx * 4 + j];
            #pragma unroll
            for (int i = 0; i < 4; ++i)
                #pragma unroll
                for (int j = 0; j < 4; ++j) acc[i][j] += a[i] * b[j];
        }
        __syncthreads();
    }
    float* zo = zbuf + (size_t)d * NW * GATES;
    #pragma unroll
    for (int i = 0; i < 4; ++i)
        #pragma unroll
        for (int j = 0; j < 4; ++j)
            zo[(size_t)(row0 + ty * 4 + i) * GATES + (col0 + tx * 4 + j)] = acc[i][j];
}

// ---------------- char LSTM pointwise: gates -> c,h, write enc ----------------
__global__ __launch_bounds__(256)
void char_pointwise(int s,
    const float* __restrict__ zbuf,
    const float* __restrict__ b_f, const float* __restrict__ b_b,
    float* __restrict__ hbuf,   // [par][dir][NW][H2]
    float* __restrict__ cbuf,   // [dir][NW][H2]
    float* __restrict__ enc)    // [TC][NW][HID]
{
    int id = blockIdx.x * blockDim.x + threadIdx.x;   // 2*NW*H2
    int d = id >> 18;
    int r = id & ((1 << 18) - 1);
    int n = r >> 8, j = r & (H2 - 1);
    const float* bias = d ? b_b : b_f;
    const float* z = zbuf + ((size_t)d * NW + n) * GATES;
    float zi = z[j]         + bias[j];
    float zf = z[H2 + j]    + bias[H2 + j];
    float zg = z[2*H2 + j]  + bias[2*H2 + j];
    float zo = z[3*H2 + j]  + bias[3*H2 + j];
    float c_old = (s == 0) ? 0.f : cbuf[(size_t)d * NW * H2 + r];
    float c = sigf(zf) * c_old + sigf(zi) * tanhf(zg);
    float h = sigf(zo) * tanhf(c);
    cbuf[(size_t)d * NW * H2 + r] = c;
    hbuf[(size_t)(((s + 1) & 1) * 2 + d) * NW * H2 + r] = h;
    int t_time = d ? (TC - 1 - s) : s;
    enc[((size_t)t_time * NW + n) * HID + d * H2 + j] = h;
}

// ---------------- attention score GEMM ----------------
__global__ __launch_bounds__(256)
void score_gemm(const float* __restrict__ enc, const float* __restrict__ aW,
                const float* __restrict__ ab, const float* __restrict__ aw,
                float* __restrict__ part)   // [TC*NW][8]
{
    __shared__ float As[16][65];
    __shared__ float Bs[16][65];
    __shared__ float red[64][17];
    const int tid = threadIdx.x;
    const int tx = tid & 15, ty = tid >> 4;
    const int row0 = blockIdx.x * 64;
    const int col0 = blockIdx.y * 64;
    float acc[4][4] = {};
    for (int kb = 0; kb < HID; kb += 16) {
        #pragma unroll
        for (int q = 0; q < 4; ++q) {
            int idx = tid + q * 256;
            int mm = idx >> 4, kk = idx & 15;
            As[kk][mm] = enc[(size_t)(row0 + mm) * HID + kb + kk];
            Bs[kk][mm] = aW[(size_t)(col0 + mm) * HID + kb + kk];
        }
        __syncthreads();
        #pragma unroll
        for (int kk = 0; kk < 16; ++kk) {
            float a[4], b[4];
            #pragma unroll
            for (int i = 0; i < 4; ++i) a[i] = As[kk][ty * 4 + i];
            #pragma unroll
            for (int j = 0; j < 4; ++j) b[j] = Bs[kk][tx * 4 + j];
            #pragma unroll
            for (int i = 0; i < 4; ++i)
                #pragma unroll
                for (int j = 0; j < 4; ++j) acc[i][j] += a[i] * b[j];
        }
        __syncthreads();
    }
    #pragma unroll
    for (int i = 0; i < 4; ++i) {
        float rs = 0.f;
        #pragma unroll
        for (int j = 0; j < 4; ++j) {
            int col = col0 + tx * 4 + j;
            rs += tanhf(acc[i][j] + ab[col]) * aw[col];
        }
        red[ty * 4 + i][tx] = rs;
    }
    __syncthreads();
    if (tid < 64) {
        float v = 0.f;
        #pragma unroll
        for (int x = 0; x < 16; ++x) v += red[tid][x];
        part[(size_t)(row0 + tid) * 8 + blockIdx.y] = v;
    }
}

// ---------------- softmax over t per word ----------------
__global__ void alpha_softmax(const float* __restrict__ part, float* __restrict__ al)
{
    int n = blockIdx.x * blockDim.x + threadIdx.x;   // NW
    float sc[TC];
    #pragma unroll
    for (int t = 0; t < TC; ++t) {
        float v = 0.f;
        #pragma unroll
        for (int q = 0; q < 8; ++q) v += part[(size_t)(t * NW + n) * 8 + q];
        sc[t] = v;
    }
    float m = -1e30f;
    #pragma unroll
    for (int t = 0; t < TC; ++t) m = fmaxf(m, sc[t]);
    float ssum = 0.f;
    #pragma unroll
    for (int t = 0; t < TC; ++t) { sc[t] = expf(sc[t] - m); ssum += sc[t]; }
    float inv = 1.f / ssum;
    #pragma unroll
    for (int t = 0; t < TC; ++t) al[t * NW + n] = sc[t] * inv;
}

// ---------------- context ----------------
__global__ void context_kernel(const float* __restrict__ al, const float* __restrict__ enc,
                               float* __restrict__ ctx)
{
    int id = blockIdx.x * blockDim.x + threadIdx.x;   // NW*HID
    int n = id >> 9, h = id & (HID - 1);
    float v = 0.f;
    #pragma unroll
    for (int t = 0; t < TC; ++t)
        v += al[t * NW + n] * enc[((size_t)t * NW + n) * HID + h];
    ctx[id] = v;
}

// ---------------- word input-projection GEMM ----------------
__global__ __launch_bounds__(256)
void word_proj_gemm(const float* __restrict__ word_emb, const int* __restrict__ word_seq,
                    const float* __restrict__ ctx,
                    const float* __restrict__ Wih_f, const float* __restrict__ b_fp,
                    const float* __restrict__ Wih_b, const float* __restrict__ b_bp,
                    float* __restrict__ Gw)   // [dir][NW][GATES]
{
    const int d = blockIdx.z;
    const float* W = d ? Wih_b : Wih_f;
    const float* bias = d ? b_bp : b_fp;
    __shared__ float As[16][65];
    __shared__ float Bs[16][65];
    const int tid = threadIdx.x;
    const int tx = tid & 15, ty = tid >> 4;
    const int row0 = blockIdx.x * 64;
    const int col0 = blockIdx.y * 64;
    float acc[4][4] = {};
    for (int kb = 0; kb < KW; kb += 16) {
        #pragma unroll
        for (int q = 0; q < 4; ++q) {
            int idx = tid + q * 256;
            int mm = idx >> 4, kk = idx & 15;
            int k = kb + kk;
            int n = row0 + mm;
            float av = 0.f, bv = 0.f;
            if (k < KW) {
                if (k < EW) av = word_emb[(size_t)word_seq[n] * EW + k];
                else        av = ctx[(size_t)n * HID + (k - EW)];
                bv = W[(size_t)(col0 + mm) * KW + k];
            }
            As[kk][mm] = av;
            Bs[kk][mm] = bv;
        }
        __syncthreads();
        #pragma unroll
        for (int kk = 0; kk < 16; ++kk) {
            float a[4], b[4];
            #pragma unroll
            for (int i = 0; i < 4; ++i) a[i] = As[kk][ty * 4 + i];
            #pragma unroll
            for (int j = 0; j < 4; ++j) b[j] = Bs[kk][tx * 4 + j];
            #pragma unroll
            for (int i = 0; i < 4; ++i)
                #pragma unroll
                for (int j = 0; j < 4; ++j) acc[i][j] += a[i] * b[j];
        }
        __syncthreads();
    }
    float* zo = Gw + (size_t)d * NW * GATES;
    #pragma unroll
    for (int i = 0; i < 4; ++i)
        #pragma unroll
        for (int j = 0; j < 4; ++j) {
            int g = col0 + tx * 4 + j;
            zo[(size_t)(row0 + ty * 4 + i) * GATES + g] = acc[i][j] + bias[g];
        }
}

// ---------------- Whh fp32 -> packed fp16 quads, thread-major ----------------
// wpk[d][q][row] (uint4) = pairs {4q..4q+3} of gate-row `row` = Whh_d[row][8q..8q+7]
__global__ __launch_bounds__(256)
void pack_whh(const float* __restrict__ Whh_fw, const float* __restrict__ Whh_bw,
              uint4* __restrict__ wpk)
{
    int id = blockIdx.x * 256 + threadIdx.x;   // 2*1024*32
    int d = id >> 15;
    int rem = id & 32767;
    int row = rem >> 5, q = rem & 31;
    const float* W = d ? Whh_bw : Whh_fw;
    const float* src = W + (size_t)row * H2 + q * 8;
    U32H p0, p1, p2, p3;
    p0.h.x = (_Float16)src[0]; p0.h.y = (_Float16)src[1];
    p1.h.x = (_Float16)src[2]; p1.h.y = (_Float16)src[3];
    p2.h.x = (_Float16)src[4]; p2.h.y = (_Float16)src[5];
    p3.h.x = (_Float16)src[6]; p3.h.y = (_Float16)src[7];
    uint4 v; v.x = p0.u; v.y = p1.u; v.z = p2.u; v.w = p3.u;
    wpk[((size_t)d * 32 + q) * 1024 + row] = v;
}

// ---------------- word BiLSTM: one persistent 1024-thread block per direction ----------------
// FEASIBLE-BUDGET + PINNED configuration (the untested cell of the r6/r7 matrix):
// 1024 threads -> 16 waves -> 4 waves/SIMD -> 128-VGPR budget (waves_per_eu(4,4)).
// Thread owns ONE gate row: quads 0..23 in 24 NAMED uint4 SSA values = 96 VGPRs,
// PINNED via empty asm so they can't be rematerialized as re-loads (r6's failure);
// 96 + ~26 working = ~122 <= 128 -> resident by construction.
// Quads 24..31 in LDS (128 KB). h packed half2 in LDS (broadcast b128 reads).
#define FDOT(hreg, wreg, acc) { U32H _h, _w; _h.u = (hreg); _w.u = (wreg); \
    acc = __builtin_amdgcn_fdot2(_h.h, _w.h, acc, false); }
#define LOADU(q) uint4 U##q = wq[(q) * 1024 + tid];
#define PINQ(U) asm volatile("" : "+v"(U.x), "+v"(U.y), "+v"(U.z), "+v"(U.w));
#define DOTQ(q) { uint4 hh = hp4[q]; \
    FDOT(hh.x, U##q.x, a0) FDOT(hh.y, U##q.y, a1) \
    FDOT(hh.z, U##q.z, a2) FDOT(hh.w, U##q.w, a3) }

__global__ __launch_bounds__(1024)
__attribute__((amdgpu_waves_per_eu(4, 4)))
void word_lstm_dir(const uint4* __restrict__ wpk,
                   const float* __restrict__ Gw,     // [dir][NW][GATES]
                   float* __restrict__ wout)         // [NW][HID]
{
    extern __shared__ float smem[];
    uint4* lw4 = (uint4*)smem;                         // 8 quads × 1024 rows = 128 KB
    float* zs = smem + 32 * 1024;                      // [1024]
    unsigned int* hpk = (unsigned int*)(zs + GATES);   // [128] packed half2

    const int d = blockIdx.x;
    const int tid = threadIdx.x;
    const float* G = Gw + (size_t)d * NW * GATES;
    const uint4* wq = wpk + (size_t)d * 32 * 1024;

    // quads 0..23 -> named SSA registers (coalesced dwordx4 loads), then pin
    LOADU(0)  LOADU(1)  LOADU(2)  LOADU(3)  LOADU(4)  LOADU(5)
    LOADU(6)  LOADU(7)  LOADU(8)  LOADU(9)  LOADU(10) LOADU(11)
    LOADU(12) LOADU(13) LOADU(14) LOADU(15) LOADU(16) LOADU(17)
    LOADU(18) LOADU(19) LOADU(20) LOADU(21) LOADU(22) LOADU(23)
    PINQ(U0)  PINQ(U1)  PINQ(U2)  PINQ(U3)  PINQ(U4)  PINQ(U5)
    PINQ(U6)  PINQ(U7)  PINQ(U8)  PINQ(U9)  PINQ(U10) PINQ(U11)
    PINQ(U12) PINQ(U13) PINQ(U14) PINQ(U15) PINQ(U16) PINQ(U17)
    PINQ(U18) PINQ(U19) PINQ(U20) PINQ(U21) PINQ(U22) PINQ(U23)
    // quads 24..31 -> LDS
    #pragma unroll
    for (int s = 0; s < 8; ++s)
        lw4[s * 1024 + tid] = wq[(24 + s) * 1024 + tid];
    if (tid < 128) hpk[tid] = 0u;
    float c = 0.f;
    __syncthreads();

    const int woff = d * H2;
    float g = G[(size_t)(d ? (NW - 1) : 0) * GATES + tid];
    for (int t = 0; t < NW; ++t) {
        const int tt = d ? (NW - 1 - t) : t;
        // prefetch next step's G (hidden under the dot)
        float gn = 0.f;
        if (t + 1 < NW) {
            const int tn = d ? (NW - 2 - t) : (t + 1);
            gn = G[(size_t)tn * GATES + tid];
        }
        float a0 = 0.f, a1 = 0.f, a2 = 0.f, a3 = 0.f;
        const uint4* hp4 = (const uint4*)hpk;
        DOTQ(0)  DOTQ(1)  DOTQ(2)  DOTQ(3)  DOTQ(4)  DOTQ(5)
        DOTQ(6)  DOTQ(7)  DOTQ(8)  DOTQ(9)  DOTQ(10) DOTQ(11)
        DOTQ(12) DOTQ(13) DOTQ(14) DOTQ(15) DOTQ(16) DOTQ(17)
        DOTQ(18) DOTQ(19) DOTQ(20) DOTQ(21) DOTQ(22) DOTQ(23)
        // quads 24..31 from LDS
        #pragma unroll
        for (int q = 24; q < 32; ++q) {
            uint4 hh = hp4[q];
            uint4 ww = lw4[(q - 24) * 1024 + tid];
            FDOT(hh.x, ww.x, a0) FDOT(hh.y, ww.y, a1)
            FDOT(hh.z, ww.z, a2) FDOT(hh.w, ww.w, a3)
        }
        zs[tid] = (a0 + a1) + (a2 + a3) + g;
        __syncthreads();
        if (tid < H2) {
            float zi = zs[tid],        zf = zs[H2 + tid];
            float zg = zs[2*H2 + tid], zo = zs[3*H2 + tid];
            c = sigf(zf) * c + sigf(zi) * tanhf(zg);
            float h = sigf(zo) * tanhf(c);
            ((_Float16*)hpk)[tid] = (_Float16)h;
            wout[(size_t)tt * HID + woff + tid] = h;
        }
        g = gn;
        __syncthreads();
    }
}

// ---------------- output heads ----------------
__global__ __launch_bounds__(64)
void heads_kernel(const float* __restrict__ wout,
                  const float* __restrict__ hpW, const float* __restrict__ hpb,
                  const float* __restrict__ hnW, const float* __restrict__ hnb,
                  float* __restrict__ out)
{
    const int n = blockIdx.x;
    const int tid = threadIdx.x;
    __shared__ float v[HID];
    #pragma unroll
    for (int q = 0; q < 8; ++q) v[tid + q * 64] = wout[(size_t)n * HID + tid + q * 64];
    __syncthreads();
    float sc = 0.f;
    if (tid < NPOS) {
        for (int k = 0; k < HID; ++k) sc += v[k] * hpW[(size_t)tid * HID + k];
        sc += hpb[tid];
    } else {
        int cc = tid - NPOS;
        for (int k = 0; k < HID; ++k) sc += v[k] * hnW[(size_t)cc * HID + k];
        sc += hnb[cc];
    }
    __shared__ float ssc[64];
    __shared__ float lsep, lsen;
    ssc[tid] = sc;
    __syncthreads();
    if (tid == 0) {
        float m = -1e30f;
        for (int i = 0; i < NPOS; ++i) m = fmaxf(m, ssc[i]);
        float su = 0.f;
        for (int i = 0; i < NPOS; ++i) su += expf(ssc[i] - m);
        lsep = m + logf(su);
    }
    if (tid == 32) {
        float m = -1e30f;
        for (int i = NPOS; i < 64; ++i) m = fmaxf(m, ssc[i]);
        float su = 0.f;
        for (int i = NPOS; i < 64; ++i) su += expf(ssc[i] - m);
        lsen = m + logf(su);
    }
    __syncthreads();
    if (tid < NPOS) out[(size_t)n * NPOS + tid] = sc - lsep;
    else            out[(size_t)NW * NPOS + (size_t)n * NNER + (tid - NPOS)] = sc - lsen;
}

// ---------------- host launch ----------------
extern "C" void kernel_launch(void* const* d_in, const int* in_sizes, int n_in,
                              void* d_out, int out_size, void* d_ws, size_t ws_size,
                              hipStream_t stream) {
    const float* char_emb = (const float*)d_in[0];
    const float* word_emb = (const float*)d_in[1];
    const float* cWih_f   = (const float*)d_in[2];
    const float* cWhh_f   = (const float*)d_in[3];
    const float* cb_f     = (const float*)d_in[4];
    const float* cWih_b   = (const float*)d_in[5];
    const float* cWhh_b   = (const float*)d_in[6];
    const float* cb_b     = (const float*)d_in[7];
    const float* wWih_f   = (const float*)d_in[8];
    const float* wWhh_f   = (const float*)d_in[9];
    const float* wb_f     = (const float*)d_in[10];
    const float* wWih_b   = (const float*)d_in[11];
    const float* wWhh_b   = (const float*)d_in[12];
    const float* wb_b     = (const float*)d_in[13];
    const float* aW       = (const float*)d_in[14];
    const float* ab       = (const float*)d_in[15];
    const float* aw       = (const float*)d_in[16];
    const float* hpW      = (const float*)d_in[17];
    const float* hpb      = (const float*)d_in[18];
    const float* hnW      = (const float*)d_in[19];
    const float* hnb      = (const float*)d_in[20];
    const int*   word_seq = (const int*)d_in[21];
    const int*   char_seq = (const int*)d_in[22];
    float* out = (float*)d_out;
    float* ws  = (float*)d_ws;

    const size_t OFF_ENC  = 0;
    const size_t OFF_Z    = OFF_ENC  + (size_t)TC * NW * HID;
    const size_t OFF_CH   = OFF_Z    + (size_t)2 * NW * GATES;
    const size_t OFF_CC   = OFF_CH   + (size_t)4 * NW * H2;
    const size_t OFF_CTX  = OFF_CC   + (size_t)2 * NW * H2;
    const size_t OFF_WOUT = OFF_CTX  + (size_t)NW * HID;
    const size_t OFF_PART = OFF_WOUT + (size_t)NW * HID;
    const size_t OFF_AL   = OFF_PART + (size_t)TC * NW * 8;
    const size_t OFF_WPK  = OFF_AL   + (size_t)TC * NW;     // 2*32*1024 uint4 = 262144 floats

    // --- char BiLSTM, 16 steps ---
    dim3 gchar(NW / 64, GATES / 64, 2);
    for (int s = 0; s < TC; ++s) {
        char_gate_gemm<<<gchar, 256, 0, stream>>>(s, char_emb, char_seq,
            cWih_f, cWhh_f, cWih_b, cWhh_b, ws + OFF_CH, ws + OFF_Z);
        char_pointwise<<<(2 * NW * H2) / 256, 256, 0, stream>>>(s, ws + OFF_Z,
            cb_f, cb_b, ws + OFF_CH, ws + OFF_CC, ws + OFF_ENC);
    }

    // --- pack word-LSTM recurrent weights to fp16 quads ---
    pack_whh<<<(2 * 1024 * 32) / 256, 256, 0, stream>>>(wWhh_f, wWhh_b, (uint4*)(ws + OFF_WPK));

    // --- attention ---
    score_gemm<<<dim3(TC * NW / 64, HID / 64), 256, 0, stream>>>(
        ws + OFF_ENC, aW, ab, aw, ws + OFF_PART);
    alpha_softmax<<<NW / 256, 256, 0, stream>>>(ws + OFF_PART, ws + OFF_AL);
    context_kernel<<<(NW * HID) / 256, 256, 0, stream>>>(ws + OFF_AL, ws + OFF_ENC, ws + OFF_CTX);

    // --- word input projection ---
    word_proj_gemm<<<dim3(NW / 64, GATES / 64, 2), 256, 0, stream>>>(
        word_emb, word_seq, ws + OFF_CTX, wWih_f, wb_f, wWih_b, wb_b, ws + OFF_Z);

    // --- word BiLSTM: 2 independent persistent 1024-thread blocks ---
    const int lds_bytes = (32 * 1024 + GATES + 128) * 4;   // 135680
    hipFuncSetAttribute((const void*)word_lstm_dir,
                        hipFuncAttributeMaxDynamicSharedMemorySize, lds_bytes);
    word_lstm_dir<<<2, 1024, lds_bytes, stream>>>(
        (const uint4*)(ws + OFF_WPK), ws + OFF_Z, ws + OFF_WOUT);

    // --- heads ---
    heads_kernel<<<NW, 64, 0, stream>>>(ws + OFF_WOUT, hpW, hpb, hnW, hnb, out);
}

// Round 10
// 4365.177 us; speedup vs baseline: 2.0898x; 2.0898x over previous
//
#include <hip/hip_runtime.h>
#include <hip/hip_bf16.h>
#include <hip/hip_fp16.h>
#include <math.h>

#define NW 1024
#define TC 16
#define EC 128
#define EW 300
#define HID 512
#define H2 256
#define GATES 1024
#define KC (EC + H2)   // 384
#define KW (EW + HID)  // 812
#define NPOS 48
#define NNER 16

typedef _Float16 h2v __attribute__((ext_vector_type(2)));
union U32H { unsigned int u; h2v h; float f; };

__device__ __forceinline__ float sigf(float x) { return 1.f / (1.f + expf(-x)); }

// ---------------- char LSTM gate GEMM: z[d][n][g] = x_t[n]·Wih[g] + h[n]·Whh[g] ----------------
__global__ __launch_bounds__(256)
void char_gate_gemm(int s,
    const float* __restrict__ char_emb, const int* __restrict__ char_seq,
    const float* __restrict__ Wih_f, const float* __restrict__ Whh_f,
    const float* __restrict__ Wih_b, const float* __restrict__ Whh_b,
    const float* __restrict__ hbuf,   // [par][dir][NW][H2]
    float* __restrict__ zbuf)         // [dir][NW][GATES]
{
    const int d = blockIdx.z;
    const float* Wih = d ? Wih_b : Wih_f;
    const float* Whh = d ? Whh_b : Whh_f;
    const int t_time = d ? (TC - 1 - s) : s;
    const float* hprev = hbuf + (size_t)((s & 1) * 2 + d) * NW * H2;

    __shared__ float As[16][65];
    __shared__ float Bs[16][65];
    const int tid = threadIdx.x;
    const int tx = tid & 15, ty = tid >> 4;
    const int row0 = blockIdx.x * 64;
    const int col0 = blockIdx.y * 64;
    float acc[4][4] = {};
    for (int kb = 0; kb < KC; kb += 16) {
        #pragma unroll
        for (int q = 0; q < 4; ++q) {
            int idx = tid + q * 256;
            int mm = idx >> 4, kk = idx & 15;
            int k = kb + kk;
            int n = row0 + mm;
            float av;
            if (k < EC) {
                int ci = char_seq[n * TC + t_time];
                av = char_emb[(size_t)ci * EC + k];
            } else {
                av = (s == 0) ? 0.f : hprev[(size_t)n * H2 + (k - EC)];
            }
            As[kk][mm] = av;
            int g = col0 + mm;
            Bs[kk][mm] = (k < EC) ? Wih[(size_t)g * EC + k] : Whh[(size_t)g * H2 + (k - EC)];
        }
        __syncthreads();
        #pragma unroll
        for (int kk = 0; kk < 16; ++kk) {
            float a[4], b[4];
            #pragma unroll
            for (int i = 0; i < 4; ++i) a[i] = As[kk][ty * 4 + i];
            #pragma unroll
            for (int j = 0; j < 4; ++j) b[j] = Bs[kk][tx * 4 + j];
            #pragma unroll
            for (int i = 0; i < 4; ++i)
                #pragma unroll
                for (int j = 0; j < 4; ++j) acc[i][j] += a[i] * b[j];
        }
        __syncthreads();
    }
    float* zo = zbuf + (size_t)d * NW * GATES;
    #pragma unroll
    for (int i = 0; i < 4; ++i)
        #pragma unroll
        for (int j = 0; j < 4; ++j)
            zo[(size_t)(row0 + ty * 4 + i) * GATES + (col0 + tx * 4 + j)] = acc[i][j];
}

// ---------------- char LSTM pointwise: gates -> c,h, write enc ----------------
__global__ __launch_bounds__(256)
void char_pointwise(int s,
    const float* __restrict__ zbuf,
    const float* __restrict__ b_f, const float* __restrict__ b_b,
    float* __restrict__ hbuf,   // [par][dir][NW][H2]
    float* __restrict__ cbuf,   // [dir][NW][H2]
    float* __restrict__ enc)    // [TC][NW][HID]
{
    int id = blockIdx.x * blockDim.x + threadIdx.x;   // 2*NW*H2
    int d = id >> 18;
    int r = id & ((1 << 18) - 1);
    int n = r >> 8, j = r & (H2 - 1);
    const float* bias = d ? b_b : b_f;
    const float* z = zbuf + ((size_t)d * NW + n) * GATES;
    float zi = z[j]         + bias[j];
    float zf = z[H2 + j]    + bias[H2 + j];
    float zg = z[2*H2 + j]  + bias[2*H2 + j];
    float zo = z[3*H2 + j]  + bias[3*H2 + j];
    float c_old = (s == 0) ? 0.f : cbuf[(size_t)d * NW * H2 + r];
    float c = sigf(zf) * c_old + sigf(zi) * tanhf(zg);
    float h = sigf(zo) * tanhf(c);
    cbuf[(size_t)d * NW * H2 + r] = c;
    hbuf[(size_t)(((s + 1) & 1) * 2 + d) * NW * H2 + r] = h;
    int t_time = d ? (TC - 1 - s) : s;
    enc[((size_t)t_time * NW + n) * HID + d * H2 + j] = h;
}

// ---------------- attention score GEMM ----------------
__global__ __launch_bounds__(256)
void score_gemm(const float* __restrict__ enc, const float* __restrict__ aW,
                const float* __restrict__ ab, const float* __restrict__ aw,
                float* __restrict__ part)   // [TC*NW][8]
{
    __shared__ float As[16][65];
    __shared__ float Bs[16][65];
    __shared__ float red[64][17];
    const int tid = threadIdx.x;
    const int tx = tid & 15, ty = tid >> 4;
    const int row0 = blockIdx.x * 64;
    const int col0 = blockIdx.y * 64;
    float acc[4][4] = {};
    for (int kb = 0; kb < HID; kb += 16) {
        #pragma unroll
        for (int q = 0; q < 4; ++q) {
            int idx = tid + q * 256;
            int mm = idx >> 4, kk = idx & 15;
            As[kk][mm] = enc[(size_t)(row0 + mm) * HID + kb + kk];
            Bs[kk][mm] = aW[(size_t)(col0 + mm) * HID + kb + kk];
        }
        __syncthreads();
        #pragma unroll
        for (int kk = 0; kk < 16; ++kk) {
            float a[4], b[4];
            #pragma unroll
            for (int i = 0; i < 4; ++i) a[i] = As[kk][ty * 4 + i];
            #pragma unroll
            for (int j = 0; j < 4; ++j) b[j] = Bs[kk][tx * 4 + j];
            #pragma unroll
            for (int i = 0; i < 4; ++i)
                #pragma unroll
                for (int j = 0; j < 4; ++j) acc[i][j] += a[i] * b[j];
        }
        __syncthreads();
    }
    #pragma unroll
    for (int i = 0; i < 4; ++i) {
        float rs = 0.f;
        #pragma unroll
        for (int j = 0; j < 4; ++j) {
            int col = col0 + tx * 4 + j;
            rs += tanhf(acc[i][j] + ab[col]) * aw[col];
        }
        red[ty * 4 + i][tx] = rs;
    }
    __syncthreads();
    if (tid < 64) {
        float v = 0.f;
        #pragma unroll
        for (int x = 0; x < 16; ++x) v += red[tid][x];
        part[(size_t)(row0 + tid) * 8 + blockIdx.y] = v;
    }
}

// ---------------- softmax over t per word ----------------
__global__ void alpha_softmax(const float* __restrict__ part, float* __restrict__ al)
{
    int n = blockIdx.x * blockDim.x + threadIdx.x;   // NW
    float sc[TC];
    #pragma unroll
    for (int t = 0; t < TC; ++t) {
        float v = 0.f;
        #pragma unroll
        for (int q = 0; q < 8; ++q) v += part[(size_t)(t * NW + n) * 8 + q];
        sc[t] = v;
    }
    float m = -1e30f;
    #pragma unroll
    for (int t = 0; t < TC; ++t) m = fmaxf(m, sc[t]);
    float ssum = 0.f;
    #pragma unroll
    for (int t = 0; t < TC; ++t) { sc[t] = expf(sc[t] - m); ssum += sc[t]; }
    float inv = 1.f / ssum;
    #pragma unroll
    for (int t = 0; t < TC; ++t) al[t * NW + n] = sc[t] * inv;
}

// ---------------- context ----------------
__global__ void context_kernel(const float* __restrict__ al, const float* __restrict__ enc,
                               float* __restrict__ ctx)
{
    int id = blockIdx.x * blockDim.x + threadIdx.x;   // NW*HID
    int n = id >> 9, h = id & (HID - 1);
    float v = 0.f;
    #pragma unroll
    for (int t = 0; t < TC; ++t)
        v += al[t * NW + n] * enc[((size_t)t * NW + n) * HID + h];
    ctx[id] = v;
}

// ---------------- word input-projection GEMM ----------------
__global__ __launch_bounds__(256)
void word_proj_gemm(const float* __restrict__ word_emb, const int* __restrict__ word_seq,
                    const float* __restrict__ ctx,
                    const float* __restrict__ Wih_f, const float* __restrict__ b_fp,
                    const float* __restrict__ Wih_b, const float* __restrict__ b_bp,
                    float* __restrict__ Gw)   // [dir][NW][GATES]
{
    const int d = blockIdx.z;
    const float* W = d ? Wih_b : Wih_f;
    const float* bias = d ? b_bp : b_fp;
    __shared__ float As[16][65];
    __shared__ float Bs[16][65];
    const int tid = threadIdx.x;
    const int tx = tid & 15, ty = tid >> 4;
    const int row0 = blockIdx.x * 64;
    const int col0 = blockIdx.y * 64;
    float acc[4][4] = {};
    for (int kb = 0; kb < KW; kb += 16) {
        #pragma unroll
        for (int q = 0; q < 4; ++q) {
            int idx = tid + q * 256;
            int mm = idx >> 4, kk = idx & 15;
            int k = kb + kk;
            int n = row0 + mm;
            float av = 0.f, bv = 0.f;
            if (k < KW) {
                if (k < EW) av = word_emb[(size_t)word_seq[n] * EW + k];
                else        av = ctx[(size_t)n * HID + (k - EW)];
                bv = W[(size_t)(col0 + mm) * KW + k];
            }
            As[kk][mm] = av;
            Bs[kk][mm] = bv;
        }
        __syncthreads();
        #pragma unroll
        for (int kk = 0; kk < 16; ++kk) {
            float a[4], b[4];
            #pragma unroll
            for (int i = 0; i < 4; ++i) a[i] = As[kk][ty * 4 + i];
            #pragma unroll
            for (int j = 0; j < 4; ++j) b[j] = Bs[kk][tx * 4 + j];
            #pragma unroll
            for (int i = 0; i < 4; ++i)
                #pragma unroll
                for (int j = 0; j < 4; ++j) acc[i][j] += a[i] * b[j];
        }
        __syncthreads();
    }
    float* zo = Gw + (size_t)d * NW * GATES;
    #pragma unroll
    for (int i = 0; i < 4; ++i)
        #pragma unroll
        for (int j = 0; j < 4; ++j) {
            int g = col0 + tx * 4 + j;
            zo[(size_t)(row0 + ty * 4 + i) * GATES + g] = acc[i][j] + bias[g];
        }
}

// ---------------- Whh fp32 -> fp16 uint2, 4-block-partitioned layout ----------------
// wpk2[((d*4+b)*32 + pp)*512 + tid]: for block b, thread tid (local row rl=tid>>1,
// k-half kh=tid&1), pp-th uint2 = weight pairs {kh*64+2pp, kh*64+2pp+1} of gate row
// grow = (rl>>6)*H2 + b*64 + (rl&63).
__global__ __launch_bounds__(256)
void pack_whh2(const float* __restrict__ Whh_fw, const float* __restrict__ Whh_bw,
               uint2* __restrict__ wpk2)
{
    int id = blockIdx.x * 256 + threadIdx.x;   // 2*4*32*512 = 131072
    int tid = id & 511;
    int pp  = (id >> 9) & 31;
    int b   = (id >> 14) & 3;
    int d   = id >> 16;
    int rl = tid >> 1, kh = tid & 1;
    int grow = (rl >> 6) * H2 + b * 64 + (rl & 63);
    const float* W = d ? Whh_bw : Whh_fw;
    const float* src = W + (size_t)grow * H2 + 2 * (kh * 64 + 2 * pp);
    U32H p0, p1;
    p0.h.x = (_Float16)src[0]; p0.h.y = (_Float16)src[1];
    p1.h.x = (_Float16)src[2]; p1.h.y = (_Float16)src[3];
    uint2 v; v.x = p0.u; v.y = p1.u;
    wpk2[id] = v;
}

// ---------------- word BiLSTM: 4 blocks per direction, weights fully in LDS ----------------
// 8 blocks x 512 threads (all co-resident; fwd blocks 0-3, bwd 4-7, no inter-dir sync).
// Block owns 64 hidden units = 256 gate rows; its 128 KB fp16 weight slice lives in LDS
// (zero VGPR pressure -> nothing for the allocator to spill, the r2-r9 failure mode).
// Per step: 64 fdot2/thread from LDS + shfl pair-reduce -> pointwise(64 thr) ->
// 128 B h-slice exchange via global hbuf with release/acquire flags (r1-proven pattern).
#define FDOT(hreg, wreg, acc) { U32H _h, _w; _h.u = (hreg); _w.u = (wreg); \
    acc = __builtin_amdgcn_fdot2(_h.h, _w.h, acc, false); }

__global__ __launch_bounds__(512)
void word_lstm4(const uint2* __restrict__ wpk2,
                const float* __restrict__ Gw,      // [dir][NW][GATES]
                float* __restrict__ wout,          // [NW][HID]
                unsigned int* __restrict__ hbuf,   // [dir][2 slots][128] packed half2
                unsigned int* __restrict__ flags)  // [dir][NW]
{
    extern __shared__ float smem[];
    uint2* lw2 = (uint2*)smem;                          // 32*512 uint2 = 128 KB
    unsigned int* hl = (unsigned int*)(lw2 + 32 * 512); // [128]
    float* zs = (float*)(hl + 128);                     // [256]

    const int blk = blockIdx.x;        // 0..7
    const int d = blk >> 2, b = blk & 3;
    const int tid = threadIdx.x;
    const int rl = tid >> 1, kh = tid & 1;
    const int grow = (rl >> 6) * H2 + b * 64 + (rl & 63);
    const float* G = Gw + (size_t)d * NW * GATES;
    const uint2* wq = wpk2 + ((size_t)blk * 32) * 512;
    unsigned int* myflags = flags + d * NW;
    unsigned int* hb = hbuf + d * 256;

    // stage this block's weight slice into LDS (conflict-free column layout)
    #pragma unroll
    for (int pp = 0; pp < 32; ++pp)
        lw2[pp * 512 + tid] = wq[pp * 512 + tid];
    if (tid < 128) hl[tid] = 0u;
    float c = 0.f;
    __syncthreads();

    for (int t = 0; t < NW; ++t) {
        const int tt = d ? (NW - 1 - t) : t;
        float gv = G[(size_t)tt * GATES + grow];
        float a0 = 0.f, a1 = 0.f, a2 = 0.f, a3 = 0.f;
        const uint4* hl4 = (const uint4*)hl;
        #pragma unroll
        for (int pq = 0; pq < 16; ++pq) {
            uint4 hh = hl4[kh * 16 + pq];
            uint2 w0 = lw2[(2 * pq) * 512 + tid];
            uint2 w1 = lw2[(2 * pq + 1) * 512 + tid];
            FDOT(hh.x, w0.x, a0) FDOT(hh.y, w0.y, a1)
            FDOT(hh.z, w1.x, a2) FDOT(hh.w, w1.y, a3)
        }
        float acc = (a0 + a1) + (a2 + a3);
        acc += __shfl_xor(acc, 1);
        if (!kh) zs[rl] = acc + gv;
        __syncthreads();

        const int slot = (t & 1) << 7;
        if (tid < 64) {
            float zi = zs[tid],       zf = zs[64 + tid];
            float zg = zs[128 + tid], zo = zs[192 + tid];
            c = sigf(zf) * c + sigf(zi) * tanhf(zg);
            float h = sigf(zo) * tanhf(c);
            wout[(size_t)tt * HID + d * H2 + b * 64 + tid] = h;
            float hn = __shfl_down(h, 1);
            if (!(tid & 1)) {
                U32H pk; pk.h.x = (_Float16)h; pk.h.y = (_Float16)hn;
                hb[slot + b * 32 + (tid >> 1)] = pk.u;
            }
            __threadfence();
        }
        __syncthreads();
        if (tid == 0) {
            __hip_atomic_fetch_add(&myflags[t], 1u, __ATOMIC_RELEASE, __HIP_MEMORY_SCOPE_AGENT);
            while (__hip_atomic_load(&myflags[t], __ATOMIC_ACQUIRE, __HIP_MEMORY_SCOPE_AGENT) < 4u) {}
        }
        __syncthreads();
        if (tid < 128) hl[tid] = hb[slot + tid];
        __syncthreads();
    }
}

// ---------------- output heads ----------------
__global__ __launch_bounds__(64)
void heads_kernel(const float* __restrict__ wout,
                  const float* __restrict__ hpW, const float* __restrict__ hpb,
                  const float* __restrict__ hnW, const float* __restrict__ hnb,
                  float* __restrict__ out)
{
    const int n = blockIdx.x;
    const int tid = threadIdx.x;
    __shared__ float v[HID];
    #pragma unroll
    for (int q = 0; q < 8; ++q) v[tid + q * 64] = wout[(size_t)n * HID + tid + q * 64];
    __syncthreads();
    float sc = 0.f;
    if (tid < NPOS) {
        for (int k = 0; k < HID; ++k) sc += v[k] * hpW[(size_t)tid * HID + k];
        sc += hpb[tid];
    } else {
        int cc = tid - NPOS;
        for (int k = 0; k < HID; ++k) sc += v[k] * hnW[(size_t)cc * HID + k];
        sc += hnb[cc];
    }
    __shared__ float ssc[64];
    __shared__ float lsep, lsen;
    ssc[tid] = sc;
    __syncthreads();
    if (tid == 0) {
        float m = -1e30f;
        for (int i = 0; i < NPOS; ++i) m = fmaxf(m, ssc[i]);
        float su = 0.f;
        for (int i = 0; i < NPOS; ++i) su += expf(ssc[i] - m);
        lsep = m + logf(su);
    }
    if (tid == 32) {
        float m = -1e30f;
        for (int i = NPOS; i < 64; ++i) m = fmaxf(m, ssc[i]);
        float su = 0.f;
        for (int i = NPOS; i < 64; ++i) su += expf(ssc[i] - m);
        lsen = m + logf(su);
    }
    __syncthreads();
    if (tid < NPOS) out[(size_t)n * NPOS + tid] = sc - lsep;
    else            out[(size_t)NW * NPOS + (size_t)n * NNER + (tid - NPOS)] = sc - lsen;
}

// ---------------- host launch ----------------
extern "C" void kernel_launch(void* const* d_in, const int* in_sizes, int n_in,
                              void* d_out, int out_size, void* d_ws, size_t ws_size,
                              hipStream_t stream) {
    const float* char_emb = (const float*)d_in[0];
    const float* word_emb = (const float*)d_in[1];
    const float* cWih_f   = (const float*)d_in[2];
    const float* cWhh_f   = (const float*)d_in[3];
    const float* cb_f     = (const float*)d_in[4];
    const float* cWih_b   = (const float*)d_in[5];
    const float* cWhh_b   = (const float*)d_in[6];
    const float* cb_b     = (const float*)d_in[7];
    const float* wWih_f   = (const float*)d_in[8];
    const float* wWhh_f   = (const float*)d_in[9];
    const float* wb_f     = (const float*)d_in[10];
    const float* wWih_b   = (const float*)d_in[11];
    const float* wWhh_b   = (const float*)d_in[12];
    const float* wb_b     = (const float*)d_in[13];
    const float* aW       = (const float*)d_in[14];
    const float* ab       = (const float*)d_in[15];
    const float* aw       = (const float*)d_in[16];
    const float* hpW      = (const float*)d_in[17];
    const float* hpb      = (const float*)d_in[18];
    const float* hnW      = (const float*)d_in[19];
    const float* hnb      = (const float*)d_in[20];
    const int*   word_seq = (const int*)d_in[21];
    const int*   char_seq = (const int*)d_in[22];
    float* out = (float*)d_out;
    float* ws  = (float*)d_ws;

    const size_t OFF_ENC  = 0;
    const size_t OFF_Z    = OFF_ENC  + (size_t)TC * NW * HID;
    const size_t OFF_CH   = OFF_Z    + (size_t)2 * NW * GATES;
    const size_t OFF_CC   = OFF_CH   + (size_t)4 * NW * H2;
    const size_t OFF_CTX  = OFF_CC   + (size_t)2 * NW * H2;
    const size_t OFF_WOUT = OFF_CTX  + (size_t)NW * HID;
    const size_t OFF_PART = OFF_WOUT + (size_t)NW * HID;
    const size_t OFF_AL   = OFF_PART + (size_t)TC * NW * 8;
    const size_t OFF_WPK  = OFF_AL   + (size_t)TC * NW;     // 131072 uint2 = 262144 floats
    const size_t OFF_HB   = OFF_WPK  + 262144;              // 512 u32
    const size_t OFF_FLG  = OFF_HB   + 512;                 // 2048 u32

    // zero the per-step flags (only region needing a fresh zero every call)
    hipMemsetAsync(ws + OFF_FLG, 0, 2 * NW * sizeof(unsigned int), stream);

    // --- char BiLSTM, 16 steps ---
    dim3 gchar(NW / 64, GATES / 64, 2);
    for (int s = 0; s < TC; ++s) {
        char_gate_gemm<<<gchar, 256, 0, stream>>>(s, char_emb, char_seq,
            cWih_f, cWhh_f, cWih_b, cWhh_b, ws + OFF_CH, ws + OFF_Z);
        char_pointwise<<<(2 * NW * H2) / 256, 256, 0, stream>>>(s, ws + OFF_Z,
            cb_f, cb_b, ws + OFF_CH, ws + OFF_CC, ws + OFF_ENC);
    }

    // --- pack word-LSTM recurrent weights (4-block partitioned fp16 layout) ---
    pack_whh2<<<(2 * 4 * 32 * 512) / 256, 256, 0, stream>>>(
        wWhh_f, wWhh_b, (uint2*)(ws + OFF_WPK));

    // --- attention ---
    score_gemm<<<dim3(TC * NW / 64, HID / 64), 256, 0, stream>>>(
        ws + OFF_ENC, aW, ab, aw, ws + OFF_PART);
    alpha_softmax<<<NW / 256, 256, 0, stream>>>(ws + OFF_PART, ws + OFF_AL);
    context_kernel<<<(NW * HID) / 256, 256, 0, stream>>>(ws + OFF_AL, ws + OFF_ENC, ws + OFF_CTX);

    // --- word input projection ---
    word_proj_gemm<<<dim3(NW / 64, GATES / 64, 2), 256, 0, stream>>>(
        word_emb, word_seq, ws + OFF_CTX, wWih_f, wb_f, wWih_b, wb_b, ws + OFF_Z);

    // --- word BiLSTM: 8 blocks (4 per direction), weights in LDS ---
    const int lds_bytes = 32 * 512 * 8 + 128 * 4 + 256 * 4;   // 132608
    hipFuncSetAttribute((const void*)word_lstm4,
                        hipFuncAttributeMaxDynamicSharedMemorySize, lds_bytes);
    word_lstm4<<<8, 512, lds_bytes, stream>>>(
        (const uint2*)(ws + OFF_WPK), ws + OFF_Z, ws + OFF_WOUT,
        (unsigned int*)(ws + OFF_HB), (unsigned int*)(ws + OFF_FLG));

    // --- heads ---
    heads_kernel<<<NW, 64, 0, stream>>>(ws + OFF_WOUT, hpW, hpb, hnW, hnb, out);
}

// Round 11
// 4073.121 us; speedup vs baseline: 2.2397x; 1.0717x over previous
//
#include <hip/hip_runtime.h>
#include <hip/hip_bf16.h>
#include <hip/hip_fp16.h>
#include <math.h>

#define NW 1024
#define TC 16
#define EC 128
#define EW 300
#define HID 512
#define H2 256
#define GATES 1024
#define KC (EC + H2)   // 384
#define KW (EW + HID)  // 812
#define NPOS 48
#define NNER 16

typedef _Float16 h2v __attribute__((ext_vector_type(2)));
union U32H { unsigned int u; h2v h; float f; };

__device__ __forceinline__ float sigf(float x) { return 1.f / (1.f + expf(-x)); }

// ---------------- char LSTM gate GEMM ----------------
__global__ __launch_bounds__(256)
void char_gate_gemm(int s,
    const float* __restrict__ char_emb, const int* __restrict__ char_seq,
    const float* __restrict__ Wih_f, const float* __restrict__ Whh_f,
    const float* __restrict__ Wih_b, const float* __restrict__ Whh_b,
    const float* __restrict__ hbuf,   // [par][dir][NW][H2]
    float* __restrict__ zbuf)         // [dir][NW][GATES]
{
    const int d = blockIdx.z;
    const float* Wih = d ? Wih_b : Wih_f;
    const float* Whh = d ? Whh_b : Whh_f;
    const int t_time = d ? (TC - 1 - s) : s;
    const float* hprev = hbuf + (size_t)((s & 1) * 2 + d) * NW * H2;

    __shared__ float As[16][65];
    __shared__ float Bs[16][65];
    const int tid = threadIdx.x;
    const int tx = tid & 15, ty = tid >> 4;
    const int row0 = blockIdx.x * 64;
    const int col0 = blockIdx.y * 64;
    float acc[4][4] = {};
    for (int kb = 0; kb < KC; kb += 16) {
        #pragma unroll
        for (int q = 0; q < 4; ++q) {
            int idx = tid + q * 256;
            int mm = idx >> 4, kk = idx & 15;
            int k = kb + kk;
            int n = row0 + mm;
            float av;
            if (k < EC) {
                int ci = char_seq[n * TC + t_time];
                av = char_emb[(size_t)ci * EC + k];
            } else {
                av = (s == 0) ? 0.f : hprev[(size_t)n * H2 + (k - EC)];
            }
            As[kk][mm] = av;
            int g = col0 + mm;
            Bs[kk][mm] = (k < EC) ? Wih[(size_t)g * EC + k] : Whh[(size_t)g * H2 + (k - EC)];
        }
        __syncthreads();
        #pragma unroll
        for (int kk = 0; kk < 16; ++kk) {
            float a[4], b[4];
            #pragma unroll
            for (int i = 0; i < 4; ++i) a[i] = As[kk][ty * 4 + i];
            #pragma unroll
            for (int j = 0; j < 4; ++j) b[j] = Bs[kk][tx * 4 + j];
            #pragma unroll
            for (int i = 0; i < 4; ++i)
                #pragma unroll
                for (int j = 0; j < 4; ++j) acc[i][j] += a[i] * b[j];
        }
        __syncthreads();
    }
    float* zo = zbuf + (size_t)d * NW * GATES;
    #pragma unroll
    for (int i = 0; i < 4; ++i)
        #pragma unroll
        for (int j = 0; j < 4; ++j)
            zo[(size_t)(row0 + ty * 4 + i) * GATES + (col0 + tx * 4 + j)] = acc[i][j];
}

// ---------------- char LSTM pointwise ----------------
__global__ __launch_bounds__(256)
void char_pointwise(int s,
    const float* __restrict__ zbuf,
    const float* __restrict__ b_f, const float* __restrict__ b_b,
    float* __restrict__ hbuf, float* __restrict__ cbuf, float* __restrict__ enc)
{
    int id = blockIdx.x * blockDim.x + threadIdx.x;   // 2*NW*H2
    int d = id >> 18;
    int r = id & ((1 << 18) - 1);
    int n = r >> 8, j = r & (H2 - 1);
    const float* bias = d ? b_b : b_f;
    const float* z = zbuf + ((size_t)d * NW + n) * GATES;
    float zi = z[j]         + bias[j];
    float zf = z[H2 + j]    + bias[H2 + j];
    float zg = z[2*H2 + j]  + bias[2*H2 + j];
    float zo = z[3*H2 + j]  + bias[3*H2 + j];
    float c_old = (s == 0) ? 0.f : cbuf[(size_t)d * NW * H2 + r];
    float c = sigf(zf) * c_old + sigf(zi) * tanhf(zg);
    float h = sigf(zo) * tanhf(c);
    cbuf[(size_t)d * NW * H2 + r] = c;
    hbuf[(size_t)(((s + 1) & 1) * 2 + d) * NW * H2 + r] = h;
    int t_time = d ? (TC - 1 - s) : s;
    enc[((size_t)t_time * NW + n) * HID + d * H2 + j] = h;
}

// ---------------- attention score GEMM ----------------
__global__ __launch_bounds__(256)
void score_gemm(const float* __restrict__ enc, const float* __restrict__ aW,
                const float* __restrict__ ab, const float* __restrict__ aw,
                float* __restrict__ part)
{
    __shared__ float As[16][65];
    __shared__ float Bs[16][65];
    __shared__ float red[64][17];
    const int tid = threadIdx.x;
    const int tx = tid & 15, ty = tid >> 4;
    const int row0 = blockIdx.x * 64;
    const int col0 = blockIdx.y * 64;
    float acc[4][4] = {};
    for (int kb = 0; kb < HID; kb += 16) {
        #pragma unroll
        for (int q = 0; q < 4; ++q) {
            int idx = tid + q * 256;
            int mm = idx >> 4, kk = idx & 15;
            As[kk][mm] = enc[(size_t)(row0 + mm) * HID + kb + kk];
            Bs[kk][mm] = aW[(size_t)(col0 + mm) * HID + kb + kk];
        }
        __syncthreads();
        #pragma unroll
        for (int kk = 0; kk < 16; ++kk) {
            float a[4], b[4];
            #pragma unroll
            for (int i = 0; i < 4; ++i) a[i] = As[kk][ty * 4 + i];
            #pragma unroll
            for (int j = 0; j < 4; ++j) b[j] = Bs[kk][tx * 4 + j];
            #pragma unroll
            for (int i = 0; i < 4; ++i)
                #pragma unroll
                for (int j = 0; j < 4; ++j) acc[i][j] += a[i] * b[j];
        }
        __syncthreads();
    }
    #pragma unroll
    for (int i = 0; i < 4; ++i) {
        float rs = 0.f;
        #pragma unroll
        for (int j = 0; j < 4; ++j) {
            int col = col0 + tx * 4 + j;
            rs += tanhf(acc[i][j] + ab[col]) * aw[col];
        }
        red[ty * 4 + i][tx] = rs;
    }
    __syncthreads();
    if (tid < 64) {
        float v = 0.f;
        #pragma unroll
        for (int x = 0; x < 16; ++x) v += red[tid][x];
        part[(size_t)(row0 + tid) * 8 + blockIdx.y] = v;
    }
}

// ---------------- softmax over t per word ----------------
__global__ void alpha_softmax(const float* __restrict__ part, float* __restrict__ al)
{
    int n = blockIdx.x * blockDim.x + threadIdx.x;
    float sc[TC];
    #pragma unroll
    for (int t = 0; t < TC; ++t) {
        float v = 0.f;
        #pragma unroll
        for (int q = 0; q < 8; ++q) v += part[(size_t)(t * NW + n) * 8 + q];
        sc[t] = v;
    }
    float m = -1e30f;
    #pragma unroll
    for (int t = 0; t < TC; ++t) m = fmaxf(m, sc[t]);
    float ssum = 0.f;
    #pragma unroll
    for (int t = 0; t < TC; ++t) { sc[t] = expf(sc[t] - m); ssum += sc[t]; }
    float inv = 1.f / ssum;
    #pragma unroll
    for (int t = 0; t < TC; ++t) al[t * NW + n] = sc[t] * inv;
}

// ---------------- context ----------------
__global__ void context_kernel(const float* __restrict__ al, const float* __restrict__ enc,
                               float* __restrict__ ctx)
{
    int id = blockIdx.x * blockDim.x + threadIdx.x;
    int n = id >> 9, h = id & (HID - 1);
    float v = 0.f;
    #pragma unroll
    for (int t = 0; t < TC; ++t)
        v += al[t * NW + n] * enc[((size_t)t * NW + n) * HID + h];
    ctx[id] = v;
}

// ---------------- word input-projection GEMM ----------------
__global__ __launch_bounds__(256)
void word_proj_gemm(const float* __restrict__ word_emb, const int* __restrict__ word_seq,
                    const float* __restrict__ ctx,
                    const float* __restrict__ Wih_f, const float* __restrict__ b_fp,
                    const float* __restrict__ Wih_b, const float* __restrict__ b_bp,
                    float* __restrict__ Gw)
{
    const int d = blockIdx.z;
    const float* W = d ? Wih_b : Wih_f;
    const float* bias = d ? b_bp : b_fp;
    __shared__ float As[16][65];
    __shared__ float Bs[16][65];
    const int tid = threadIdx.x;
    const int tx = tid & 15, ty = tid >> 4;
    const int row0 = blockIdx.x * 64;
    const int col0 = blockIdx.y * 64;
    float acc[4][4] = {};
    for (int kb = 0; kb < KW; kb += 16) {
        #pragma unroll
        for (int q = 0; q < 4; ++q) {
            int idx = tid + q * 256;
            int mm = idx >> 4, kk = idx & 15;
            int k = kb + kk;
            int n = row0 + mm;
            float av = 0.f, bv = 0.f;
            if (k < KW) {
                if (k < EW) av = word_emb[(size_t)word_seq[n] * EW + k];
                else        av = ctx[(size_t)n * HID + (k - EW)];
                bv = W[(size_t)(col0 + mm) * KW + k];
            }
            As[kk][mm] = av;
            Bs[kk][mm] = bv;
        }
        __syncthreads();
        #pragma unroll
        for (int kk = 0; kk < 16; ++kk) {
            float a[4], b[4];
            #pragma unroll
            for (int i = 0; i < 4; ++i) a[i] = As[kk][ty * 4 + i];
            #pragma unroll
            for (int j = 0; j < 4; ++j) b[j] = Bs[kk][tx * 4 + j];
            #pragma unroll
            for (int i = 0; i < 4; ++i)
                #pragma unroll
                for (int j = 0; j < 4; ++j) acc[i][j] += a[i] * b[j];
        }
        __syncthreads();
    }
    float* zo = Gw + (size_t)d * NW * GATES;
    #pragma unroll
    for (int i = 0; i < 4; ++i)
        #pragma unroll
        for (int j = 0; j < 4; ++j) {
            int g = col0 + tx * 4 + j;
            zo[(size_t)(row0 + ty * 4 + i) * GATES + g] = acc[i][j] + bias[g];
        }
}

// ---------------- Whh fp32 -> packed fp16 quads, thread-major ----------------
__global__ __launch_bounds__(256)
void pack_whh(const float* __restrict__ Whh_fw, const float* __restrict__ Whh_bw,
              uint4* __restrict__ wpk)
{
    int id = blockIdx.x * 256 + threadIdx.x;   // 2*1024*32
    int d = id >> 15;
    int rem = id & 32767;
    int row = rem >> 5, q = rem & 31;
    const float* W = d ? Whh_bw : Whh_fw;
    const float* src = W + (size_t)row * H2 + q * 8;
    U32H p0, p1, p2, p3;
    p0.h.x = (_Float16)src[0]; p0.h.y = (_Float16)src[1];
    p1.h.x = (_Float16)src[2]; p1.h.y = (_Float16)src[3];
    p2.h.x = (_Float16)src[4]; p2.h.y = (_Float16)src[5];
    p3.h.x = (_Float16)src[6]; p3.h.y = (_Float16)src[7];
    uint4 v; v.x = p0.u; v.y = p1.u; v.z = p2.u; v.w = p3.u;
    wpk[((size_t)d * 32 + q) * 1024 + row] = v;
}

// ---------------- word BiLSTM: one persistent 512-thread block per direction ----------------
// Single-CU per direction -> only __syncthreads (no 2.5 µs/step cross-XCD flag RT, the
// r10-measured wall). Weight residency uses the FULL unified register file:
//   Row A (gate row tid):      32 quads = 128 u32 in AGPRs via "a"-constraint inline asm
//                              (hard allocation + SSA dataflow; arch-VGPR cap untouched).
//   Row B (gate row tid+512):  quads 0..15 in LDS (128 KB), quads 16..31 streamed from
//                              L2 each step (128 KB/step, issued at loop top).
// Arch pressure ~100 <= 128 (the allocator's observed cap); total/wave ~230 <= 256.
#define FDOT(hreg, wreg, acc) { U32H _h, _w; _h.u = (hreg); _w.u = (wreg); \
    acc = __builtin_amdgcn_fdot2(_h.h, _w.h, acc, false); }
#define DEFQ(q) unsigned int Aq##q##_0, Aq##q##_1, Aq##q##_2, Aq##q##_3;
#define STASHQ(q) { uint4 w = wq[(q) * 1024 + tid]; \
    asm volatile("v_accvgpr_write_b32 %0, %1" : "=a"(Aq##q##_0) : "v"(w.x)); \
    asm volatile("v_accvgpr_write_b32 %0, %1" : "=a"(Aq##q##_1) : "v"(w.y)); \
    asm volatile("v_accvgpr_write_b32 %0, %1" : "=a"(Aq##q##_2) : "v"(w.z)); \
    asm volatile("v_accvgpr_write_b32 %0, %1" : "=a"(Aq##q##_3) : "v"(w.w)); }
#define DOTAQ(q, hh) { unsigned int t0, t1, t2, t3; \
    asm volatile("v_accvgpr_read_b32 %0, %1" : "=v"(t0) : "a"(Aq##q##_0)); \
    asm volatile("v_accvgpr_read_b32 %0, %1" : "=v"(t1) : "a"(Aq##q##_1)); \
    asm volatile("v_accvgpr_read_b32 %0, %1" : "=v"(t2) : "a"(Aq##q##_2)); \
    asm volatile("v_accvgpr_read_b32 %0, %1" : "=v"(t3) : "a"(Aq##q##_3)); \
    FDOT(hh.x, t0, a0) FDOT(hh.y, t1, a1) FDOT(hh.z, t2, a2) FDOT(hh.w, t3, a3) }
#define STEPQ_L(q) { uint4 hh = hl4[q]; DOTAQ(q, hh) \
    uint4 wb = lw4[(q) * 512 + tid]; \
    FDOT(hh.x, wb.x, b0) FDOT(hh.y, wb.y, b1) FDOT(hh.z, wb.z, b2) FDOT(hh.w, wb.w, b3) }
#define STEPQ_S(q, S) { uint4 hh = hl4[q]; DOTAQ(q, hh) \
    FDOT(hh.x, S.x, b0) FDOT(hh.y, S.y, b1) FDOT(hh.z, S.z, b2) FDOT(hh.w, S.w, b3) }
#define LOADS(s) uint4 S##s = sq[(s) * 1024];

__global__ __launch_bounds__(512)
void word_lstm_dir(const uint4* __restrict__ wpk,
                   const float* __restrict__ Gw,     // [dir][NW][GATES]
                   float* __restrict__ wout)         // [NW][HID]
{
    extern __shared__ float smem[];
    uint4* lw4 = (uint4*)smem;                         // 16 slots × 512 = 128 KB
    float* zs = smem + 32 * 1024;                      // [1024]
    unsigned int* hpk = (unsigned int*)(zs + GATES);   // [128] packed half2

    const int d = blockIdx.x;
    const int tid = threadIdx.x;
    const float* G = Gw + (size_t)d * NW * GATES;
    const uint4* wq = wpk + (size_t)d * 32 * 1024;

    // Row A quads 0..31 -> AGPRs
    DEFQ(0)  DEFQ(1)  DEFQ(2)  DEFQ(3)  DEFQ(4)  DEFQ(5)  DEFQ(6)  DEFQ(7)
    DEFQ(8)  DEFQ(9)  DEFQ(10) DEFQ(11) DEFQ(12) DEFQ(13) DEFQ(14) DEFQ(15)
    DEFQ(16) DEFQ(17) DEFQ(18) DEFQ(19) DEFQ(20) DEFQ(21) DEFQ(22) DEFQ(23)
    DEFQ(24) DEFQ(25) DEFQ(26) DEFQ(27) DEFQ(28) DEFQ(29) DEFQ(30) DEFQ(31)
    STASHQ(0)  STASHQ(1)  STASHQ(2)  STASHQ(3)  STASHQ(4)  STASHQ(5)  STASHQ(6)  STASHQ(7)
    STASHQ(8)  STASHQ(9)  STASHQ(10) STASHQ(11) STASHQ(12) STASHQ(13) STASHQ(14) STASHQ(15)
    STASHQ(16) STASHQ(17) STASHQ(18) STASHQ(19) STASHQ(20) STASHQ(21) STASHQ(22) STASHQ(23)
    STASHQ(24) STASHQ(25) STASHQ(26) STASHQ(27) STASHQ(28) STASHQ(29) STASHQ(30) STASHQ(31)

    // Row B quads 0..15 -> LDS
    #pragma unroll
    for (int s = 0; s < 16; ++s)
        lw4[s * 512 + tid] = wq[s * 1024 + 512 + tid];
    if (tid < 128) hpk[tid] = 0u;
    float c0 = 0.f, c1 = 0.f;
    __syncthreads();

    const uint4* sq = wq + 16 * 1024 + 512 + tid;      // Row B quads 16..31 (streamed)
    const int woff = d * H2;
    float g0 = G[(size_t)(d ? (NW - 1) : 0) * GATES + tid];
    float g1 = G[(size_t)(d ? (NW - 1) : 0) * GATES + 512 + tid];
    for (int t = 0; t < NW; ++t) {
        const int tt = d ? (NW - 1 - t) : t;
        // issue the 16 streamed row-B quads (L2-resident; latency hidden under row-A dots)
        LOADS(0)  LOADS(1)  LOADS(2)  LOADS(3)  LOADS(4)  LOADS(5)  LOADS(6)  LOADS(7)
        LOADS(8)  LOADS(9)  LOADS(10) LOADS(11) LOADS(12) LOADS(13) LOADS(14) LOADS(15)
        float gn0 = 0.f, gn1 = 0.f;
        if (t + 1 < NW) {
            const int tn = d ? (NW - 2 - t) : (t + 1);
            gn0 = G[(size_t)tn * GATES + tid];
            gn1 = G[(size_t)tn * GATES + 512 + tid];
        }
        float a0 = 0.f, a1 = 0.f, a2 = 0.f, a3 = 0.f;
        float b0 = 0.f, b1 = 0.f, b2 = 0.f, b3 = 0.f;
        const uint4* hl4 = (const uint4*)hpk;
        STEPQ_L(0)  STEPQ_L(1)  STEPQ_L(2)  STEPQ_L(3)
        STEPQ_L(4)  STEPQ_L(5)  STEPQ_L(6)  STEPQ_L(7)
        STEPQ_L(8)  STEPQ_L(9)  STEPQ_L(10) STEPQ_L(11)
        STEPQ_L(12) STEPQ_L(13) STEPQ_L(14) STEPQ_L(15)
        STEPQ_S(16, S0)  STEPQ_S(17, S1)  STEPQ_S(18, S2)  STEPQ_S(19, S3)
        STEPQ_S(20, S4)  STEPQ_S(21, S5)  STEPQ_S(22, S6)  STEPQ_S(23, S7)
        STEPQ_S(24, S8)  STEPQ_S(25, S9)  STEPQ_S(26, S10) STEPQ_S(27, S11)
        STEPQ_S(28, S12) STEPQ_S(29, S13) STEPQ_S(30, S14) STEPQ_S(31, S15)
        zs[tid]       = (a0 + a1) + (a2 + a3) + g0;
        zs[512 + tid] = (b0 + b1) + (b2 + b3) + g1;
        __syncthreads();
        if (tid < 128) {
            const int u0 = 2 * tid, u1 = u0 + 1;
            float zi0 = zs[u0],       zi1 = zs[u1];
            float zf0 = zs[256 + u0], zf1 = zs[256 + u1];
            float zg0 = zs[512 + u0], zg1 = zs[512 + u1];
            float zo0 = zs[768 + u0], zo1 = zs[768 + u1];
            c0 = sigf(zf0) * c0 + sigf(zi0) * tanhf(zg0);
            float h0 = sigf(zo0) * tanhf(c0);
            c1 = sigf(zf1) * c1 + sigf(zi1) * tanhf(zg1);
            float h1 = sigf(zo1) * tanhf(c1);
            U32H hp; hp.h.x = (_Float16)h0; hp.h.y = (_Float16)h1;
            hpk[tid] = hp.u;
            float2 hv; hv.x = h0; hv.y = h1;
            *(float2*)&wout[(size_t)tt * HID + woff + u0] = hv;
        }
        g0 = gn0; g1 = gn1;
        __syncthreads();
    }
}

// ---------------- output heads ----------------
__global__ __launch_bounds__(64)
void heads_kernel(const float* __restrict__ wout,
                  const float* __restrict__ hpW, const float* __restrict__ hpb,
                  const float* __restrict__ hnW, const float* __restrict__ hnb,
                  float* __restrict__ out)
{
    const int n = blockIdx.x;
    const int tid = threadIdx.x;
    __shared__ float v[HID];
    #pragma unroll
    for (int q = 0; q < 8; ++q) v[tid + q * 64] = wout[(size_t)n * HID + tid + q * 64];
    __syncthreads();
    float sc = 0.f;
    if (tid < NPOS) {
        for (int k = 0; k < HID; ++k) sc += v[k] * hpW[(size_t)tid * HID + k];
        sc += hpb[tid];
    } else {
        int cc = tid - NPOS;
        for (int k = 0; k < HID; ++k) sc += v[k] * hnW[(size_t)cc * HID + k];
        sc += hnb[cc];
    }
    __shared__ float ssc[64];
    __shared__ float lsep, lsen;
    ssc[tid] = sc;
    __syncthreads();
    if (tid == 0) {
        float m = -1e30f;
        for (int i = 0; i < NPOS; ++i) m = fmaxf(m, ssc[i]);
        float su = 0.f;
        for (int i = 0; i < NPOS; ++i) su += expf(ssc[i] - m);
        lsep = m + logf(su);
    }
    if (tid == 32) {
        float m = -1e30f;
        for (int i = NPOS; i < 64; ++i) m = fmaxf(m, ssc[i]);
        float su = 0.f;
        for (int i = NPOS; i < 64; ++i) su += expf(ssc[i] - m);
        lsen = m + logf(su);
    }
    __syncthreads();
    if (tid < NPOS) out[(size_t)n * NPOS + tid] = sc - lsep;
    else            out[(size_t)NW * NPOS + (size_t)n * NNER + (tid - NPOS)] = sc - lsen;
}

// ---------------- host launch ----------------
extern "C" void kernel_launch(void* const* d_in, const int* in_sizes, int n_in,
                              void* d_out, int out_size, void* d_ws, size_t ws_size,
                              hipStream_t stream) {
    const float* char_emb = (const float*)d_in[0];
    const float* word_emb = (const float*)d_in[1];
    const float* cWih_f   = (const float*)d_in[2];
    const float* cWhh_f   = (const float*)d_in[3];
    const float* cb_f     = (const float*)d_in[4];
    const float* cWih_b   = (const float*)d_in[5];
    const float* cWhh_b   = (const float*)d_in[6];
    const float* cb_b     = (const float*)d_in[7];
    const float* wWih_f   = (const float*)d_in[8];
    const float* wWhh_f   = (const float*)d_in[9];
    const float* wb_f     = (const float*)d_in[10];
    const float* wWih_b   = (const float*)d_in[11];
    const float* wWhh_b   = (const float*)d_in[12];
    const float* wb_b     = (const float*)d_in[13];
    const float* aW       = (const float*)d_in[14];
    const float* ab       = (const float*)d_in[15];
    const float* aw       = (const float*)d_in[16];
    const float* hpW      = (const float*)d_in[17];
    const float* hpb      = (const float*)d_in[18];
    const float* hnW      = (const float*)d_in[19];
    const float* hnb      = (const float*)d_in[20];
    const int*   word_seq = (const int*)d_in[21];
    const int*   char_seq = (const int*)d_in[22];
    float* out = (float*)d_out;
    float* ws  = (float*)d_ws;

    const size_t OFF_ENC  = 0;
    const size_t OFF_Z    = OFF_ENC  + (size_t)TC * NW * HID;
    const size_t OFF_CH   = OFF_Z    + (size_t)2 * NW * GATES;
    const size_t OFF_CC   = OFF_CH   + (size_t)4 * NW * H2;
    const size_t OFF_CTX  = OFF_CC   + (size_t)2 * NW * H2;
    const size_t OFF_WOUT = OFF_CTX  + (size_t)NW * HID;
    const size_t OFF_PART = OFF_WOUT + (size_t)NW * HID;
    const size_t OFF_AL   = OFF_PART + (size_t)TC * NW * 8;
    const size_t OFF_WPK  = OFF_AL   + (size_t)TC * NW;     // 2*32*1024 uint4 = 262144 floats

    // --- char BiLSTM, 16 steps ---
    dim3 gchar(NW / 64, GATES / 64, 2);
    for (int s = 0; s < TC; ++s) {
        char_gate_gemm<<<gchar, 256, 0, stream>>>(s, char_emb, char_seq,
            cWih_f, cWhh_f, cWih_b, cWhh_b, ws + OFF_CH, ws + OFF_Z);
        char_pointwise<<<(2 * NW * H2) / 256, 256, 0, stream>>>(s, ws + OFF_Z,
            cb_f, cb_b, ws + OFF_CH, ws + OFF_CC, ws + OFF_ENC);
    }

    // --- pack word-LSTM recurrent weights to fp16 quads ---
    pack_whh<<<(2 * 1024 * 32) / 256, 256, 0, stream>>>(wWhh_f, wWhh_b, (uint4*)(ws + OFF_WPK));

    // --- attention ---
    score_gemm<<<dim3(TC * NW / 64, HID / 64), 256, 0, stream>>>(
        ws + OFF_ENC, aW, ab, aw, ws + OFF_PART);
    alpha_softmax<<<NW / 256, 256, 0, stream>>>(ws + OFF_PART, ws + OFF_AL);
    context_kernel<<<(NW * HID) / 256, 256, 0, stream>>>(ws + OFF_AL, ws + OFF_ENC, ws + OFF_CTX);

    // --- word input projection ---
    word_proj_gemm<<<dim3(NW / 64, GATES / 64, 2), 256, 0, stream>>>(
        word_emb, word_seq, ws + OFF_CTX, wWih_f, wb_f, wWih_b, wb_b, ws + OFF_Z);

    // --- word BiLSTM: 2 independent persistent 512-thread blocks ---
    const int lds_bytes = (32 * 1024 + GATES + 128) * 4;   // 135680
    hipFuncSetAttribute((const void*)word_lstm_dir,
                        hipFuncAttributeMaxDynamicSharedMemorySize, lds_bytes);
    word_lstm_dir<<<2, 512, lds_bytes, stream>>>(
        (const uint4*)(ws + OFF_WPK), ws + OFF_Z, ws + OFF_WOUT);

    // --- heads ---
    heads_kernel<<<NW, 64, 0, stream>>>(ws + OFF_WOUT, hpW, hpb, hnW, hnb, out);
}